// Round 15
// baseline (260.554 us; speedup 1.0000x reference)
//
#include <hip/hip_runtime.h>
#include <hip/hip_bf16.h>

#define D_MODEL 1024
#define NHEAD   16
#define DK      64
#define SEQ     2048
#define BATCH   2

typedef __attribute__((ext_vector_type(8))) short bf16x8;   // 8 bf16 = 4 VGPR
typedef __attribute__((ext_vector_type(4))) float f32x4;

static __device__ __forceinline__ ushort f2bf(float f) {
  union { float f; unsigned u; } x; x.f = f;
  unsigned r = x.u + 0x7FFF + ((x.u >> 16) & 1);   // round-to-nearest-even
  return (ushort)(r >> 16);
}
static __device__ __forceinline__ float bf2f(ushort b) {
  union { unsigned u; float f; } x; x.u = ((unsigned)b) << 16;
  return x.f;
}

template<bool F32>
static __device__ __forceinline__ bf16x8 load_chunk(const void* base, size_t eoff) {
  if constexpr (F32) {
    const float* p = (const float*)base + eoff;
    float4 a = *(const float4*)p;
    float4 b = *(const float4*)(p + 4);
    bf16x8 o;
    o[0] = (short)f2bf(a.x); o[1] = (short)f2bf(a.y);
    o[2] = (short)f2bf(a.z); o[3] = (short)f2bf(a.w);
    o[4] = (short)f2bf(b.x); o[5] = (short)f2bf(b.y);
    o[6] = (short)f2bf(b.z); o[7] = (short)f2bf(b.w);
    return o;
  } else {
    return *(const bf16x8*)((const ushort*)base + eoff);
  }
}

// ---------------- Fused QKV projection GEMM (unchanged) ----------------
// r=0: Qh = (q@Wq^T + bq) * 0.125 * log2(e)   (exp2 folding)
__global__ __launch_bounds__(512) void gemm_qkv(
    const float* __restrict__ q, const float* __restrict__ k, const float* __restrict__ v,
    const float* __restrict__ Wq, const float* __restrict__ Wk, const float* __restrict__ Wv,
    const float* __restrict__ bq, const float* __restrict__ bk, const float* __restrict__ bv,
    ushort* __restrict__ Qhb, ushort* __restrict__ Khb, ushort* __restrict__ Vtb)
{
  constexpr int K = D_MODEL;
  __shared__ __align__(16) ushort At[2][128 * 32];
  __shared__ __align__(16) ushort Bt[2][128 * 32];
  const int r = blockIdx.x >> 3;
  const float* A    = (r == 0) ? q  : (r == 1) ? k  : v;
  const float* W    = (r == 0) ? Wq : (r == 1) ? Wk : Wv;
  const float* bias = (r == 0) ? bq : (r == 1) ? bk : bv;
  const float outScale = (r == 0) ? 0.125f * 1.44269504088896f : 1.0f;

  const int tid = threadIdx.x;
  const int lane = tid & 63, wave = tid >> 6;
  const int wm = wave >> 1, wn = wave & 1;
  const int m0 = blockIdx.y * 128, n0 = (blockIdx.x & 7) * 128;
  const int row = tid >> 2, kc = tid & 3;
  const size_t aoff = (size_t)(m0 + row) * K + kc * 8;
  const size_t boff = (size_t)(n0 + row) * K + kc * 8;
  const int lchunk = (kc * 128 + row) * 8;

  bf16x8 ra = load_chunk<true>(A, aoff);
  bf16x8 rb = load_chunk<true>(W, boff);
  *(bf16x8*)&At[0][lchunk] = ra;
  *(bf16x8*)&Bt[0][lchunk] = rb;
  __syncthreads();

  f32x4 acc[2][4];
  #pragma unroll
  for (int i = 0; i < 2; ++i)
    #pragma unroll
    for (int j = 0; j < 4; ++j) acc[i][j] = (f32x4){0.f, 0.f, 0.f, 0.f};

  for (int t = 0; t < 32; ++t) {
    const int cur = t & 1;
    if (t < 31) {
      ra = load_chunk<true>(A, aoff + (size_t)(t + 1) * 32);
      rb = load_chunk<true>(W, boff + (size_t)(t + 1) * 32);
    }
    bf16x8 af[2], bfr[4];
    #pragma unroll
    for (int i = 0; i < 2; ++i)
      af[i] = *(const bf16x8*)&At[cur][((lane >> 4) * 128 + wm * 32 + i * 16 + (lane & 15)) * 8];
    #pragma unroll
    for (int j = 0; j < 4; ++j)
      bfr[j] = *(const bf16x8*)&Bt[cur][((lane >> 4) * 128 + wn * 64 + j * 16 + (lane & 15)) * 8];
    __builtin_amdgcn_s_setprio(1);
    #pragma unroll
    for (int i = 0; i < 2; ++i)
      #pragma unroll
      for (int j = 0; j < 4; ++j)
        acc[i][j] = __builtin_amdgcn_mfma_f32_16x16x32_bf16(af[i], bfr[j], acc[i][j], 0, 0, 0);
    __builtin_amdgcn_s_setprio(0);
    if (t < 31) {
      *(bf16x8*)&At[cur ^ 1][lchunk] = ra;
      *(bf16x8*)&Bt[cur ^ 1][lchunk] = rb;
    }
    __syncthreads();
  }

  #pragma unroll
  for (int i = 0; i < 2; ++i) {
    #pragma unroll
    for (int j = 0; j < 4; ++j) {
      #pragma unroll
      for (int rr = 0; rr < 4; ++rr) {
        int m = m0 + wm * 32 + i * 16 + (lane >> 4) * 4 + rr;
        int n = n0 + wn * 64 + j * 16 + (lane & 15);
        float val = (acc[i][j][rr] + bias[n]) * outScale;
        int b = m >> 11, s = m & (SEQ - 1);
        int h = n >> 6,  d = n & (DK - 1);
        if (r == 0)
          Qhb[((size_t)(b * NHEAD + h) * SEQ + s) * DK + d] = f2bf(val);
        else if (r == 1)
          Khb[((size_t)(b * NHEAD + h) * SEQ + s) * DK + d] = f2bf(val);
        else
          Vtb[((size_t)(b * NHEAD + h) * DK + d) * SEQ + s] = f2bf(val);
      }
    }
  }
}

// ---------------- Output GEMM: R12 shape (128x128, BK=32) + nontemporal C ----------------
__global__ __launch_bounds__(512) void gemm_out(
    const ushort* __restrict__ A, const float* __restrict__ B,
    const float* __restrict__ bias, float* __restrict__ C,
    int M, int N, int K)
{
  __shared__ __align__(16) ushort At[2][128 * 32];
  __shared__ __align__(16) ushort Bt[2][128 * 32];
  const int tid = threadIdx.x;
  const int lane = tid & 63, wave = tid >> 6;
  const int wm = wave >> 1, wn = wave & 1;
  const int m0 = blockIdx.y * 128, n0 = blockIdx.x * 128;
  const int row = tid >> 2, kc = tid & 3;
  const size_t aoff = (size_t)(m0 + row) * K + kc * 8;
  const size_t boff = (size_t)(n0 + row) * K + kc * 8;
  const int lchunk = (kc * 128 + row) * 8;

  bf16x8 ra = load_chunk<false>(A, aoff);
  bf16x8 rb = load_chunk<true>(B, boff);
  *(bf16x8*)&At[0][lchunk] = ra;
  *(bf16x8*)&Bt[0][lchunk] = rb;
  __syncthreads();

  f32x4 acc[2][4];
  #pragma unroll
  for (int i = 0; i < 2; ++i)
    #pragma unroll
    for (int j = 0; j < 4; ++j) acc[i][j] = (f32x4){0.f, 0.f, 0.f, 0.f};

  for (int t = 0; t < 32; ++t) {
    const int cur = t & 1;
    if (t < 31) {
      ra = load_chunk<false>(A, aoff + (size_t)(t + 1) * 32);
      rb = load_chunk<true>(B, boff + (size_t)(t + 1) * 32);
    }
    bf16x8 af[2], bfr[4];
    #pragma unroll
    for (int i = 0; i < 2; ++i)
      af[i] = *(const bf16x8*)&At[cur][((lane >> 4) * 128 + wm * 32 + i * 16 + (lane & 15)) * 8];
    #pragma unroll
    for (int j = 0; j < 4; ++j)
      bfr[j] = *(const bf16x8*)&Bt[cur][((lane >> 4) * 128 + wn * 64 + j * 16 + (lane & 15)) * 8];
    __builtin_amdgcn_s_setprio(1);
    #pragma unroll
    for (int i = 0; i < 2; ++i)
      #pragma unroll
      for (int j = 0; j < 4; ++j)
        acc[i][j] = __builtin_amdgcn_mfma_f32_16x16x32_bf16(af[i], bfr[j], acc[i][j], 0, 0, 0);
    __builtin_amdgcn_s_setprio(0);
    if (t < 31) {
      *(bf16x8*)&At[cur ^ 1][lchunk] = ra;
      *(bf16x8*)&Bt[cur ^ 1][lchunk] = rb;
    }
    __syncthreads();
  }

  #pragma unroll
  for (int i = 0; i < 2; ++i) {
    #pragma unroll
    for (int j = 0; j < 4; ++j) {
      #pragma unroll
      for (int r = 0; r < 4; ++r) {
        int m = m0 + wm * 32 + i * 16 + (lane >> 4) * 4 + r;
        int n = n0 + wn * 64 + j * 16 + (lane & 15);
        __builtin_nontemporal_store(acc[i][j][r] + bias[n], &C[(size_t)m * N + n]);
      }
    }
  }
}

// ---------------- Fused flash attention (R13 math + deferred attn stores) ----------------
// R15 change: tile kt's attn store is issued at the START of iteration kt+1
// (myP still holds kt; same-wave LDS ordering protects read-before-overwrite).
// Rationale: __syncthreads emits s_waitcnt vmcnt(0) -> the barrier at each
// iteration's end drains the attn stores; issuing them late put a full
// store-ack round trip on the critical path. Now a full compute phase
// (16 MFMA + exp2 + staging) separates issue from drain.
__global__ __launch_bounds__(512, 4) void attn_fused(
    const ushort* __restrict__ Qh, const ushort* __restrict__ Kh,
    const ushort* __restrict__ Vt, float* __restrict__ attn,
    ushort* __restrict__ ctxb)
{
  __shared__ __align__(16) ushort sK[2][64 * 64];   // 2 x 8KB, XOR-swizzled
  __shared__ __align__(16) ushort sV[2][64 * 64];   // 2 x 8KB
  __shared__ __align__(16) ushort sP[8][16 * 64];   // per-wave P tiles, 16KB

  const int tid = threadIdx.x, lane = tid & 63, wave = tid >> 6;
  const int l16 = lane & 15, lq = lane >> 4;
  const int swz = l16 & 7;
  const int bid  = blockIdx.x;
  const int sbid = (bid & 7) * 64 + (bid >> 3);     // XCD swizzle (512 = 8*64)
  const int bh = sbid >> 4;
  const int q0 = (sbid & 15) * 128;
  const ushort* Qp = Qh + ((size_t)bh * SEQ + q0) * DK;
  const ushort* Kp = Kh + (size_t)bh * SEQ * DK;
  const ushort* Vp = Vt + (size_t)bh * DK * SEQ;

  bf16x8 bq0 = *(const bf16x8*)(Qp + (wave * 16 + l16) * DK + lq * 8);
  bf16x8 bq1 = *(const bf16x8*)(Qp + (wave * 16 + l16) * DK + 32 + lq * 8);

  const int srow = tid >> 3;
  const int sc   = tid & 7;
  const int sdst = (srow * 8 + (sc ^ (srow & 7))) * 8;
  const ushort* kgsrc = Kp + (size_t)tid * 8;
  const ushort* vgsrc = Vp + (size_t)srow * SEQ + sc * 8;

  // ================= Pass A: row sums =================
  float lsum = 0.f;
  {
    bf16x8 rk = *(const bf16x8*)kgsrc;
    *(bf16x8*)&sK[0][sdst] = rk;
    __syncthreads();
    for (int kt = 0; kt < 32; ++kt) {
      const int cur = kt & 1;
      if (kt < 31) rk = *(const bf16x8*)(kgsrc + (size_t)(kt + 1) * 4096);
      __builtin_amdgcn_s_setprio(1);
      #pragma unroll
      for (int ni = 0; ni < 4; ++ni) {
        bf16x8 kf0 = *(const bf16x8*)&sK[cur][((ni * 16 + l16) * 8 + (lq ^ swz)) * 8];
        bf16x8 kf1 = *(const bf16x8*)&sK[cur][((ni * 16 + l16) * 8 + ((4 + lq) ^ swz)) * 8];
        f32x4 acc = (f32x4){0.f, 0.f, 0.f, 0.f};
        acc = __builtin_amdgcn_mfma_f32_16x16x32_bf16(kf0, bq0, acc, 0, 0, 0);
        acc = __builtin_amdgcn_mfma_f32_16x16x32_bf16(kf1, bq1, acc, 0, 0, 0);
        lsum += (exp2f(acc[0]) + exp2f(acc[1])) + (exp2f(acc[2]) + exp2f(acc[3]));
      }
      __builtin_amdgcn_s_setprio(0);
      if (kt < 31) *(bf16x8*)&sK[cur ^ 1][sdst] = rk;
      __syncthreads();
    }
  }
  lsum += __shfl_xor(lsum, 16);
  lsum += __shfl_xor(lsum, 32);
  const float iv = 1.0f / lsum;

  // ================= Pass B: attn emit + PV (P pre-normalized) =================
  f32x4 cacc[4];
  #pragma unroll
  for (int ni = 0; ni < 4; ++ni) cacc[ni] = (f32x4){0.f, 0.f, 0.f, 0.f};
  ushort* myP = sP[wave];
  const int str4 = lane >> 4, stcol = (lane & 15) * 4;   // store-pattern indices
  {
    bf16x8 rk = *(const bf16x8*)kgsrc;
    bf16x8 rv = *(const bf16x8*)vgsrc;
    __syncthreads();
    *(bf16x8*)&sK[0][sdst] = rk;
    *(bf16x8*)&sV[0][sdst] = rv;
    __syncthreads();
    for (int kt = 0; kt < 32; ++kt) {
      const int cur = kt & 1;
      // ---- deferred attn store for tile kt-1 (myP untouched since then) ----
      if (kt > 0) {
        #pragma unroll
        for (int rg = 0; rg < 4; ++rg) {
          const int pr = rg * 4 + str4;
          ushort4 pv = *(const ushort4*)&myP[(pr * 8 + ((stcol >> 3) ^ (pr & 7))) * 8 + (stcol & 7)];
          f32x4 o;
          o[0] = bf2f(pv.x);
          o[1] = bf2f(pv.y);
          o[2] = bf2f(pv.z);
          o[3] = bf2f(pv.w);
          float* ap = attn + ((size_t)(bh * SEQ + q0 + wave * 16 + pr)) * SEQ + (kt - 1) * 64 + stcol;
          __builtin_nontemporal_store(o, (f32x4*)ap);
        }
      }
      if (kt < 31) {
        rk = *(const bf16x8*)(kgsrc + (size_t)(kt + 1) * 4096);
        rv = *(const bf16x8*)(vgsrc + (size_t)(kt + 1) * 64);
      }
      __builtin_amdgcn_s_setprio(1);
      #pragma unroll
      for (int ni = 0; ni < 4; ++ni) {
        bf16x8 kf0 = *(const bf16x8*)&sK[cur][((ni * 16 + l16) * 8 + (lq ^ swz)) * 8];
        bf16x8 kf1 = *(const bf16x8*)&sK[cur][((ni * 16 + l16) * 8 + ((4 + lq) ^ swz)) * 8];
        f32x4 acc = (f32x4){0.f, 0.f, 0.f, 0.f};
        acc = __builtin_amdgcn_mfma_f32_16x16x32_bf16(kf0, bq0, acc, 0, 0, 0);
        acc = __builtin_amdgcn_mfma_f32_16x16x32_bf16(kf1, bq1, acc, 0, 0, 0);
        ushort4 pk;
        pk.x = f2bf(exp2f(acc[0]) * iv);
        pk.y = f2bf(exp2f(acc[1]) * iv);
        pk.z = f2bf(exp2f(acc[2]) * iv);
        pk.w = f2bf(exp2f(acc[3]) * iv);
        const int col = ni * 16 + lq * 4;
        *(ushort4*)&myP[(l16 * 8 + ((col >> 3) ^ swz)) * 8 + (col & 7)] = pk;
      }
      #pragma unroll
      for (int h = 0; h < 2; ++h) {
        bf16x8 pa = *(const bf16x8*)&myP[(l16 * 8 + ((h * 4 + lq) ^ swz)) * 8];
        #pragma unroll
        for (int ni = 0; ni < 4; ++ni) {
          bf16x8 vf = *(const bf16x8*)&sV[cur][((ni * 16 + l16) * 8 + ((h * 4 + lq) ^ swz)) * 8];
          cacc[ni] = __builtin_amdgcn_mfma_f32_16x16x32_bf16(pa, vf, cacc[ni], 0, 0, 0);
        }
      }
      __builtin_amdgcn_s_setprio(0);
      if (kt < 31) {
        *(bf16x8*)&sK[cur ^ 1][sdst] = rk;
        *(bf16x8*)&sV[cur ^ 1][sdst] = rv;
      }
      __syncthreads();
    }
    // final tile (kt-1 = 31) store
    #pragma unroll
    for (int rg = 0; rg < 4; ++rg) {
      const int pr = rg * 4 + str4;
      ushort4 pv = *(const ushort4*)&myP[(pr * 8 + ((stcol >> 3) ^ (pr & 7))) * 8 + (stcol & 7)];
      f32x4 o;
      o[0] = bf2f(pv.x);
      o[1] = bf2f(pv.y);
      o[2] = bf2f(pv.z);
      o[3] = bf2f(pv.w);
      float* ap = attn + ((size_t)(bh * SEQ + q0 + wave * 16 + pr)) * SEQ + 31 * 64 + stcol;
      __builtin_nontemporal_store(o, (f32x4*)ap);
    }
  }

  const int bb = bh >> 4, hh = bh & 15;
  #pragma unroll
  for (int ni = 0; ni < 4; ++ni) {
    #pragma unroll
    for (int r = 0; r < 4; ++r) {
      const int qrow = wave * 16 + lq * 4 + r;
      ctxb[((size_t)(bb * SEQ + q0 + qrow)) * D_MODEL + hh * DK + ni * 16 + l16] =
          f2bf(cacc[ni][r]);
    }
  }
}

extern "C" void kernel_launch(void* const* d_in, const int* in_sizes, int n_in,
                              void* d_out, int out_size, void* d_ws, size_t ws_size,
                              hipStream_t stream)
{
  const float* q  = (const float*)d_in[0];
  const float* k  = (const float*)d_in[1];
  const float* v  = (const float*)d_in[2];
  const float* Wq = (const float*)d_in[3];
  const float* bq = (const float*)d_in[4];
  const float* Wk = (const float*)d_in[5];
  const float* bk = (const float*)d_in[6];
  const float* Wv = (const float*)d_in[7];
  const float* bv = (const float*)d_in[8];
  const float* Wo = (const float*)d_in[9];
  const float* bo = (const float*)d_in[10];

  float* out  = (float*)d_out;
  float* attn = out + (size_t)BATCH * SEQ * D_MODEL;

  const size_t XEL = (size_t)BATCH * SEQ * D_MODEL;  // 4 Mi elems
  ushort* Qhb  = (ushort*)d_ws;
  ushort* Khb  = Qhb + XEL;
  ushort* Vtb  = Khb + XEL;
  ushort* ctxb = Vtb + XEL;   // 32 MiB total

  const int M = BATCH * SEQ;
  gemm_qkv<<<dim3(24, M / 128), 512, 0, stream>>>(q, k, v, Wq, Wk, Wv, bq, bk, bv,
                                                  Qhb, Khb, Vtb);

  attn_fused<<<dim3(BATCH * NHEAD * (SEQ / 128)), 512, 0, stream>>>(Qhb, Khb, Vtb, attn, ctxb);

  gemm_out<<<dim3(D_MODEL / 128, M / 128), 512, 0, stream>>>(ctxb, Wo, bo, out, M, D_MODEL, D_MODEL);
}

// Round 16
// 244.093 us; speedup vs baseline: 1.0674x; 1.0674x over previous
//
#include <hip/hip_runtime.h>
#include <hip/hip_bf16.h>

#define D_MODEL 1024
#define NHEAD   16
#define DK      64
#define SEQ     2048
#define BATCH   2

typedef __attribute__((ext_vector_type(8))) short bf16x8;   // 8 bf16 = 4 VGPR
typedef __attribute__((ext_vector_type(4))) float f32x4;

static __device__ __forceinline__ ushort f2bf(float f) {
  union { float f; unsigned u; } x; x.f = f;
  unsigned r = x.u + 0x7FFF + ((x.u >> 16) & 1);   // round-to-nearest-even
  return (ushort)(r >> 16);
}
static __device__ __forceinline__ float bf2f(ushort b) {
  union { unsigned u; float f; } x; x.u = ((unsigned)b) << 16;
  return x.f;
}

template<bool F32>
static __device__ __forceinline__ bf16x8 load_chunk(const void* base, size_t eoff) {
  if constexpr (F32) {
    const float* p = (const float*)base + eoff;
    float4 a = *(const float4*)p;
    float4 b = *(const float4*)(p + 4);
    bf16x8 o;
    o[0] = (short)f2bf(a.x); o[1] = (short)f2bf(a.y);
    o[2] = (short)f2bf(a.z); o[3] = (short)f2bf(a.w);
    o[4] = (short)f2bf(b.x); o[5] = (short)f2bf(b.y);
    o[6] = (short)f2bf(b.z); o[7] = (short)f2bf(b.w);
    return o;
  } else {
    return *(const bf16x8*)((const ushort*)base + eoff);
  }
}

// ---------------- Fused QKV projection GEMM (R12 exact) ----------------
__global__ __launch_bounds__(512) void gemm_qkv(
    const float* __restrict__ q, const float* __restrict__ k, const float* __restrict__ v,
    const float* __restrict__ Wq, const float* __restrict__ Wk, const float* __restrict__ Wv,
    const float* __restrict__ bq, const float* __restrict__ bk, const float* __restrict__ bv,
    ushort* __restrict__ Qhb, ushort* __restrict__ Khb, ushort* __restrict__ Vtb)
{
  constexpr int K = D_MODEL;
  __shared__ __align__(16) ushort At[2][128 * 32];
  __shared__ __align__(16) ushort Bt[2][128 * 32];
  const int r = blockIdx.x >> 3;
  const float* A    = (r == 0) ? q  : (r == 1) ? k  : v;
  const float* W    = (r == 0) ? Wq : (r == 1) ? Wk : Wv;
  const float* bias = (r == 0) ? bq : (r == 1) ? bk : bv;
  const float outScale = (r == 0) ? 0.125f : 1.0f;

  const int tid = threadIdx.x;
  const int lane = tid & 63, wave = tid >> 6;
  const int wm = wave >> 1, wn = wave & 1;
  const int m0 = blockIdx.y * 128, n0 = (blockIdx.x & 7) * 128;
  const int row = tid >> 2, kc = tid & 3;
  const size_t aoff = (size_t)(m0 + row) * K + kc * 8;
  const size_t boff = (size_t)(n0 + row) * K + kc * 8;
  const int lchunk = (kc * 128 + row) * 8;

  bf16x8 ra = load_chunk<true>(A, aoff);
  bf16x8 rb = load_chunk<true>(W, boff);
  *(bf16x8*)&At[0][lchunk] = ra;
  *(bf16x8*)&Bt[0][lchunk] = rb;
  __syncthreads();

  f32x4 acc[2][4];
  #pragma unroll
  for (int i = 0; i < 2; ++i)
    #pragma unroll
    for (int j = 0; j < 4; ++j) acc[i][j] = (f32x4){0.f, 0.f, 0.f, 0.f};

  for (int t = 0; t < 32; ++t) {
    const int cur = t & 1;
    if (t < 31) {
      ra = load_chunk<true>(A, aoff + (size_t)(t + 1) * 32);
      rb = load_chunk<true>(W, boff + (size_t)(t + 1) * 32);
    }
    bf16x8 af[2], bfr[4];
    #pragma unroll
    for (int i = 0; i < 2; ++i)
      af[i] = *(const bf16x8*)&At[cur][((lane >> 4) * 128 + wm * 32 + i * 16 + (lane & 15)) * 8];
    #pragma unroll
    for (int j = 0; j < 4; ++j)
      bfr[j] = *(const bf16x8*)&Bt[cur][((lane >> 4) * 128 + wn * 64 + j * 16 + (lane & 15)) * 8];
    __builtin_amdgcn_s_setprio(1);
    #pragma unroll
    for (int i = 0; i < 2; ++i)
      #pragma unroll
      for (int j = 0; j < 4; ++j)
        acc[i][j] = __builtin_amdgcn_mfma_f32_16x16x32_bf16(af[i], bfr[j], acc[i][j], 0, 0, 0);
    __builtin_amdgcn_s_setprio(0);
    if (t < 31) {
      *(bf16x8*)&At[cur ^ 1][lchunk] = ra;
      *(bf16x8*)&Bt[cur ^ 1][lchunk] = rb;
    }
    __syncthreads();
  }

  #pragma unroll
  for (int i = 0; i < 2; ++i) {
    #pragma unroll
    for (int j = 0; j < 4; ++j) {
      #pragma unroll
      for (int rr = 0; rr < 4; ++rr) {
        int m = m0 + wm * 32 + i * 16 + (lane >> 4) * 4 + rr;
        int n = n0 + wn * 64 + j * 16 + (lane & 15);
        float val = (acc[i][j][rr] + bias[n]) * outScale;
        int b = m >> 11, s = m & (SEQ - 1);
        int h = n >> 6,  d = n & (DK - 1);
        if (r == 0)
          Qhb[((size_t)(b * NHEAD + h) * SEQ + s) * DK + d] = f2bf(val);
        else if (r == 1)
          Khb[((size_t)(b * NHEAD + h) * SEQ + s) * DK + d] = f2bf(val);
        else
          Vtb[((size_t)(b * NHEAD + h) * DK + d) * SEQ + s] = f2bf(val);
      }
    }
  }
}

// ---------------- Output GEMM (R12 exact: 128x128, BK=32, plain stores) ----------------
__global__ __launch_bounds__(512) void gemm_out(
    const ushort* __restrict__ A, const float* __restrict__ B,
    const float* __restrict__ bias, float* __restrict__ C,
    int M, int N, int K)
{
  __shared__ __align__(16) ushort At[2][128 * 32];
  __shared__ __align__(16) ushort Bt[2][128 * 32];
  const int tid = threadIdx.x;
  const int lane = tid & 63, wave = tid >> 6;
  const int wm = wave >> 1, wn = wave & 1;
  const int m0 = blockIdx.y * 128, n0 = blockIdx.x * 128;
  const int row = tid >> 2, kc = tid & 3;
  const size_t aoff = (size_t)(m0 + row) * K + kc * 8;
  const size_t boff = (size_t)(n0 + row) * K + kc * 8;
  const int lchunk = (kc * 128 + row) * 8;

  bf16x8 ra = load_chunk<false>(A, aoff);
  bf16x8 rb = load_chunk<true>(B, boff);
  *(bf16x8*)&At[0][lchunk] = ra;
  *(bf16x8*)&Bt[0][lchunk] = rb;
  __syncthreads();

  f32x4 acc[2][4];
  #pragma unroll
  for (int i = 0; i < 2; ++i)
    #pragma unroll
    for (int j = 0; j < 4; ++j) acc[i][j] = (f32x4){0.f, 0.f, 0.f, 0.f};

  for (int t = 0; t < 32; ++t) {
    const int cur = t & 1;
    if (t < 31) {
      ra = load_chunk<false>(A, aoff + (size_t)(t + 1) * 32);
      rb = load_chunk<true>(B, boff + (size_t)(t + 1) * 32);
    }
    bf16x8 af[2], bfr[4];
    #pragma unroll
    for (int i = 0; i < 2; ++i)
      af[i] = *(const bf16x8*)&At[cur][((lane >> 4) * 128 + wm * 32 + i * 16 + (lane & 15)) * 8];
    #pragma unroll
    for (int j = 0; j < 4; ++j)
      bfr[j] = *(const bf16x8*)&Bt[cur][((lane >> 4) * 128 + wn * 64 + j * 16 + (lane & 15)) * 8];
    __builtin_amdgcn_s_setprio(1);
    #pragma unroll
    for (int i = 0; i < 2; ++i)
      #pragma unroll
      for (int j = 0; j < 4; ++j)
        acc[i][j] = __builtin_amdgcn_mfma_f32_16x16x32_bf16(af[i], bfr[j], acc[i][j], 0, 0, 0);
    __builtin_amdgcn_s_setprio(0);
    if (t < 31) {
      *(bf16x8*)&At[cur ^ 1][lchunk] = ra;
      *(bf16x8*)&Bt[cur ^ 1][lchunk] = rb;
    }
    __syncthreads();
  }

  #pragma unroll
  for (int i = 0; i < 2; ++i) {
    #pragma unroll
    for (int j = 0; j < 4; ++j) {
      #pragma unroll
      for (int r = 0; r < 4; ++r) {
        int m = m0 + wm * 32 + i * 16 + (lane >> 4) * 4 + r;
        int n = n0 + wn * 64 + j * 16 + (lane & 15);
        C[(size_t)m * N + n] = acc[i][j][r] + bias[n];
      }
    }
  }
}

// ---------------- Fused flash-style attention, 128-row blocks (R12 exact) ----------------
__global__ __launch_bounds__(512, 4) void attn_fused(
    const ushort* __restrict__ Qh, const ushort* __restrict__ Kh,
    const ushort* __restrict__ Vt, float* __restrict__ attn,
    ushort* __restrict__ ctxb)
{
  __shared__ __align__(16) ushort sK[2][64 * 64];   // 2 x 8KB, XOR-swizzled
  __shared__ __align__(16) ushort sV[2][64 * 64];   // 2 x 8KB
  __shared__ __align__(16) ushort sP[8][16 * 64];   // per-wave P tiles, 16KB
  __shared__ float sInv[128];

  const int tid = threadIdx.x, lane = tid & 63, wave = tid >> 6;
  const int l16 = lane & 15, lq = lane >> 4;
  const int swz = l16 & 7;
  // XCD swizzle: 512 blocks = 8 XCDs x 64 -> 4 consecutive bh per XCD.
  const int bid  = blockIdx.x;
  const int sbid = (bid & 7) * 64 + (bid >> 3);
  const int bh = sbid >> 4;
  const int q0 = (sbid & 15) * 128;
  const ushort* Qp = Qh + ((size_t)bh * SEQ + q0) * DK;
  const ushort* Kp = Kh + (size_t)bh * SEQ * DK;
  const ushort* Vp = Vt + (size_t)bh * DK * SEQ;

  // Q B-frags for this wave's 16 rows (persistent)
  bf16x8 bq0 = *(const bf16x8*)(Qp + (wave * 16 + l16) * DK + lq * 8);
  bf16x8 bq1 = *(const bf16x8*)(Qp + (wave * 16 + l16) * DK + 32 + lq * 8);

  // staging: thread t loads one 16B chunk per matrix per tile
  const int srow = tid >> 3;                         // 0..63 (key or d)
  const int sc   = tid & 7;                          // dk/key chunk
  const int sdst = (srow * 8 + (sc ^ (srow & 7))) * 8;
  const ushort* kgsrc = Kp + (size_t)tid * 8;        // K tile kt: + kt*4096
  const ushort* vgsrc = Vp + (size_t)srow * SEQ + sc * 8;  // V tile kt: + kt*64

  // ================= Pass A: row sums =================
  float lsum = 0.f;
  {
    bf16x8 rk = *(const bf16x8*)kgsrc;
    *(bf16x8*)&sK[0][sdst] = rk;
    __syncthreads();
    for (int kt = 0; kt < 32; ++kt) {
      const int cur = kt & 1;
      if (kt < 31) rk = *(const bf16x8*)(kgsrc + (size_t)(kt + 1) * 4096);
      __builtin_amdgcn_s_setprio(1);
      #pragma unroll
      for (int ni = 0; ni < 4; ++ni) {
        bf16x8 kf0 = *(const bf16x8*)&sK[cur][((ni * 16 + l16) * 8 + (lq ^ swz)) * 8];
        bf16x8 kf1 = *(const bf16x8*)&sK[cur][((ni * 16 + l16) * 8 + ((4 + lq) ^ swz)) * 8];
        f32x4 acc = (f32x4){0.f, 0.f, 0.f, 0.f};
        acc = __builtin_amdgcn_mfma_f32_16x16x32_bf16(kf0, bq0, acc, 0, 0, 0);
        acc = __builtin_amdgcn_mfma_f32_16x16x32_bf16(kf1, bq1, acc, 0, 0, 0);
        lsum += (__expf(acc[0]) + __expf(acc[1])) + (__expf(acc[2]) + __expf(acc[3]));
      }
      __builtin_amdgcn_s_setprio(0);
      if (kt < 31) *(bf16x8*)&sK[cur ^ 1][sdst] = rk;
      __syncthreads();
    }
  }
  lsum += __shfl_xor(lsum, 16);
  lsum += __shfl_xor(lsum, 32);
  if (lane < 16) sInv[wave * 16 + lane] = 1.0f / lsum;  // own-wave use only

  // ================= Pass B: attn emit + PV =================
  f32x4 cacc[4];
  #pragma unroll
  for (int ni = 0; ni < 4; ++ni) cacc[ni] = (f32x4){0.f, 0.f, 0.f, 0.f};
  ushort* myP = sP[wave];
  {
    bf16x8 rk = *(const bf16x8*)kgsrc;
    bf16x8 rv = *(const bf16x8*)vgsrc;
    __syncthreads();                 // all pass-A reads of sK done
    *(bf16x8*)&sK[0][sdst] = rk;
    *(bf16x8*)&sV[0][sdst] = rv;
    __syncthreads();
    for (int kt = 0; kt < 32; ++kt) {
      const int cur = kt & 1;
      if (kt < 31) {
        rk = *(const bf16x8*)(kgsrc + (size_t)(kt + 1) * 4096);
        rv = *(const bf16x8*)(vgsrc + (size_t)(kt + 1) * 64);
      }
      // QK^T + exp -> wave-private P tile
      __builtin_amdgcn_s_setprio(1);
      #pragma unroll
      for (int ni = 0; ni < 4; ++ni) {
        bf16x8 kf0 = *(const bf16x8*)&sK[cur][((ni * 16 + l16) * 8 + (lq ^ swz)) * 8];
        bf16x8 kf1 = *(const bf16x8*)&sK[cur][((ni * 16 + l16) * 8 + ((4 + lq) ^ swz)) * 8];
        f32x4 acc = (f32x4){0.f, 0.f, 0.f, 0.f};
        acc = __builtin_amdgcn_mfma_f32_16x16x32_bf16(kf0, bq0, acc, 0, 0, 0);
        acc = __builtin_amdgcn_mfma_f32_16x16x32_bf16(kf1, bq1, acc, 0, 0, 0);
        ushort4 pk;
        pk.x = f2bf(__expf(acc[0]));
        pk.y = f2bf(__expf(acc[1]));
        pk.z = f2bf(__expf(acc[2]));
        pk.w = f2bf(__expf(acc[3]));
        const int col = ni * 16 + lq * 4;
        *(ushort4*)&myP[(l16 * 8 + ((col >> 3) ^ swz)) * 8 + (col & 7)] = pk;
      }
      // PV from P tile + V tile
      #pragma unroll
      for (int h = 0; h < 2; ++h) {
        bf16x8 pa = *(const bf16x8*)&myP[(l16 * 8 + ((h * 4 + lq) ^ swz)) * 8];
        #pragma unroll
        for (int ni = 0; ni < 4; ++ni) {
          bf16x8 vf = *(const bf16x8*)&sV[cur][((ni * 16 + l16) * 8 + ((h * 4 + lq) ^ swz)) * 8];
          cacc[ni] = __builtin_amdgcn_mfma_f32_16x16x32_bf16(pa, vf, cacc[ni], 0, 0, 0);
        }
      }
      __builtin_amdgcn_s_setprio(0);
      // stage next tile (writes to the buffer no one reads this iteration)
      if (kt < 31) {
        *(bf16x8*)&sK[cur ^ 1][sdst] = rk;
        *(bf16x8*)&sV[cur ^ 1][sdst] = rv;
      }
      // attn store: full-line nontemporal, wave's 16 rows x 64 keys
      {
        const int r4 = lane >> 4, c16 = lane & 15;
        const int col = c16 * 4;
        #pragma unroll
        for (int rg = 0; rg < 4; ++rg) {
          const int pr = rg * 4 + r4;
          const float iv = sInv[wave * 16 + pr];
          ushort4 pv = *(const ushort4*)&myP[(pr * 8 + ((col >> 3) ^ (pr & 7))) * 8 + (col & 7)];
          f32x4 o;
          o[0] = bf2f(pv.x) * iv;
          o[1] = bf2f(pv.y) * iv;
          o[2] = bf2f(pv.z) * iv;
          o[3] = bf2f(pv.w) * iv;
          float* ap = attn + ((size_t)(bh * SEQ + q0 + wave * 16 + pr)) * SEQ + kt * 64 + col;
          __builtin_nontemporal_store(o, (f32x4*)ap);
        }
      }
      __syncthreads();
    }
  }

  // ctx write: wave covers all keys -> acc complete, no cross-wave reduce
  const int bb = bh >> 4, hh = bh & 15;
  #pragma unroll
  for (int ni = 0; ni < 4; ++ni) {
    #pragma unroll
    for (int r = 0; r < 4; ++r) {
      const int qrow = wave * 16 + lq * 4 + r;
      const float iv = sInv[qrow];
      ctxb[((size_t)(bb * SEQ + q0 + qrow)) * D_MODEL + hh * DK + ni * 16 + l16] =
          f2bf(cacc[ni][r] * iv);
    }
  }
}

extern "C" void kernel_launch(void* const* d_in, const int* in_sizes, int n_in,
                              void* d_out, int out_size, void* d_ws, size_t ws_size,
                              hipStream_t stream)
{
  const float* q  = (const float*)d_in[0];
  const float* k  = (const float*)d_in[1];
  const float* v  = (const float*)d_in[2];
  const float* Wq = (const float*)d_in[3];
  const float* bq = (const float*)d_in[4];
  const float* Wk = (const float*)d_in[5];
  const float* bk = (const float*)d_in[6];
  const float* Wv = (const float*)d_in[7];
  const float* bv = (const float*)d_in[8];
  const float* Wo = (const float*)d_in[9];
  const float* bo = (const float*)d_in[10];

  float* out  = (float*)d_out;
  float* attn = out + (size_t)BATCH * SEQ * D_MODEL;

  const size_t XEL = (size_t)BATCH * SEQ * D_MODEL;  // 4 Mi elems
  ushort* Qhb  = (ushort*)d_ws;
  ushort* Khb  = Qhb + XEL;
  ushort* Vtb  = Khb + XEL;
  ushort* ctxb = Vtb + XEL;   // 32 MiB total

  const int M = BATCH * SEQ;
  gemm_qkv<<<dim3(24, M / 128), 512, 0, stream>>>(q, k, v, Wq, Wk, Wv, bq, bk, bv,
                                                  Qhb, Khb, Vtb);

  attn_fused<<<dim3(BATCH * NHEAD * (SEQ / 128)), 512, 0, stream>>>(Qhb, Khb, Vtb, attn, ctxb);

  gemm_out<<<dim3(D_MODEL / 128, M / 128), 512, 0, stream>>>(ctxb, Wo, bo, out, M, D_MODEL, D_MODEL);
}

// Round 17
// 222.939 us; speedup vs baseline: 1.1687x; 1.0949x over previous
//
#include <hip/hip_runtime.h>
#include <hip/hip_bf16.h>

#define D_MODEL 1024
#define NHEAD   16
#define DK      64
#define SEQ     2048
#define BATCH   2

typedef __attribute__((ext_vector_type(8))) short bf16x8;   // 8 bf16 = 4 VGPR
typedef __attribute__((ext_vector_type(4))) float f32x4;

static __device__ __forceinline__ ushort f2bf(float f) {
  union { float f; unsigned u; } x; x.f = f;
  unsigned r = x.u + 0x7FFF + ((x.u >> 16) & 1);   // round-to-nearest-even
  return (ushort)(r >> 16);
}
static __device__ __forceinline__ float bf2f(ushort b) {
  union { unsigned u; float f; } x; x.u = ((unsigned)b) << 16;
  return x.f;
}

static __device__ __forceinline__ bf16x8 ld_bf8(const ushort* p) {
  return *(const bf16x8*)p;
}

// ---------------- one-shot fp32 -> bf16 convert (R3-proven shape) ----------------
// GEMM staging re-reads each A-row x8 (N/BN) and each W-row x32 (M/BM);
// converting inside the GEMM pays 4B loads + cvt VALU on every re-read.
// Converting ONCE here halves all staging bytes and strips cvt from hot loops.
__global__ __launch_bounds__(256) void convert_all(
    const float* __restrict__ q, const float* __restrict__ k, const float* __restrict__ v,
    const float* __restrict__ wq, const float* __restrict__ wk,
    const float* __restrict__ wv, const float* __restrict__ wo,
    ushort* __restrict__ qb, ushort* __restrict__ kb, ushort* __restrict__ vb,
    ushort* __restrict__ wqb, ushort* __restrict__ wkb,
    ushort* __restrict__ wvb, ushort* __restrict__ wob)
{
  int bid = blockIdx.x;
  const float* src; ushort* dst; int seg;
  if      (bid < 2048) { src = q;  dst = qb;  seg = bid; }
  else if (bid < 4096) { src = k;  dst = kb;  seg = bid - 2048; }
  else if (bid < 6144) { src = v;  dst = vb;  seg = bid - 4096; }
  else if (bid < 6656) { src = wq; dst = wqb; seg = bid - 6144; }
  else if (bid < 7168) { src = wk; dst = wkb; seg = bid - 6656; }
  else if (bid < 7680) { src = wv; dst = wvb; seg = bid - 7168; }
  else                 { src = wo; dst = wob; seg = bid - 7680; }
  size_t base = (size_t)seg * 2048 + (size_t)threadIdx.x * 8;
  float4 a = *(const float4*)(src + base);
  float4 b = *(const float4*)(src + base + 4);
  bf16x8 o;
  o[0] = (short)f2bf(a.x); o[1] = (short)f2bf(a.y); o[2] = (short)f2bf(a.z); o[3] = (short)f2bf(a.w);
  o[4] = (short)f2bf(b.x); o[5] = (short)f2bf(b.y); o[6] = (short)f2bf(b.z); o[7] = (short)f2bf(b.w);
  *(bf16x8*)(dst + base) = o;
}

// ---------------- Fused QKV projection GEMM (R12 structure, bf16 inputs) ----------------
__global__ __launch_bounds__(512) void gemm_qkv(
    const ushort* __restrict__ q, const ushort* __restrict__ k, const ushort* __restrict__ v,
    const ushort* __restrict__ Wq, const ushort* __restrict__ Wk, const ushort* __restrict__ Wv,
    const float* __restrict__ bq, const float* __restrict__ bk, const float* __restrict__ bv,
    ushort* __restrict__ Qhb, ushort* __restrict__ Khb, ushort* __restrict__ Vtb)
{
  constexpr int K = D_MODEL;
  __shared__ __align__(16) ushort At[2][128 * 32];
  __shared__ __align__(16) ushort Bt[2][128 * 32];
  const int r = blockIdx.x >> 3;
  const ushort* A    = (r == 0) ? q  : (r == 1) ? k  : v;
  const ushort* W    = (r == 0) ? Wq : (r == 1) ? Wk : Wv;
  const float* bias  = (r == 0) ? bq : (r == 1) ? bk : bv;
  const float outScale = (r == 0) ? 0.125f : 1.0f;

  const int tid = threadIdx.x;
  const int lane = tid & 63, wave = tid >> 6;
  const int wm = wave >> 1, wn = wave & 1;
  const int m0 = blockIdx.y * 128, n0 = (blockIdx.x & 7) * 128;
  const int row = tid >> 2, kc = tid & 3;
  const size_t aoff = (size_t)(m0 + row) * K + kc * 8;
  const size_t boff = (size_t)(n0 + row) * K + kc * 8;
  const int lchunk = (kc * 128 + row) * 8;

  bf16x8 ra = ld_bf8(A + aoff);
  bf16x8 rb = ld_bf8(W + boff);
  *(bf16x8*)&At[0][lchunk] = ra;
  *(bf16x8*)&Bt[0][lchunk] = rb;
  __syncthreads();

  f32x4 acc[2][4];
  #pragma unroll
  for (int i = 0; i < 2; ++i)
    #pragma unroll
    for (int j = 0; j < 4; ++j) acc[i][j] = (f32x4){0.f, 0.f, 0.f, 0.f};

  for (int t = 0; t < 32; ++t) {
    const int cur = t & 1;
    if (t < 31) {
      ra = ld_bf8(A + aoff + (size_t)(t + 1) * 32);
      rb = ld_bf8(W + boff + (size_t)(t + 1) * 32);
    }
    bf16x8 af[2], bfr[4];
    #pragma unroll
    for (int i = 0; i < 2; ++i)
      af[i] = *(const bf16x8*)&At[cur][((lane >> 4) * 128 + wm * 32 + i * 16 + (lane & 15)) * 8];
    #pragma unroll
    for (int j = 0; j < 4; ++j)
      bfr[j] = *(const bf16x8*)&Bt[cur][((lane >> 4) * 128 + wn * 64 + j * 16 + (lane & 15)) * 8];
    __builtin_amdgcn_s_setprio(1);
    #pragma unroll
    for (int i = 0; i < 2; ++i)
      #pragma unroll
      for (int j = 0; j < 4; ++j)
        acc[i][j] = __builtin_amdgcn_mfma_f32_16x16x32_bf16(af[i], bfr[j], acc[i][j], 0, 0, 0);
    __builtin_amdgcn_s_setprio(0);
    if (t < 31) {
      *(bf16x8*)&At[cur ^ 1][lchunk] = ra;
      *(bf16x8*)&Bt[cur ^ 1][lchunk] = rb;
    }
    __syncthreads();
  }

  #pragma unroll
  for (int i = 0; i < 2; ++i) {
    #pragma unroll
    for (int j = 0; j < 4; ++j) {
      #pragma unroll
      for (int rr = 0; rr < 4; ++rr) {
        int m = m0 + wm * 32 + i * 16 + (lane >> 4) * 4 + rr;
        int n = n0 + wn * 64 + j * 16 + (lane & 15);
        float val = (acc[i][j][rr] + bias[n]) * outScale;
        int b = m >> 11, s = m & (SEQ - 1);
        int h = n >> 6,  d = n & (DK - 1);
        if (r == 0)
          Qhb[((size_t)(b * NHEAD + h) * SEQ + s) * DK + d] = f2bf(val);
        else if (r == 1)
          Khb[((size_t)(b * NHEAD + h) * SEQ + s) * DK + d] = f2bf(val);
        else
          Vtb[((size_t)(b * NHEAD + h) * DK + d) * SEQ + s] = f2bf(val);
      }
    }
  }
}

// ---------------- Output GEMM (R12 structure, bf16 W) ----------------
__global__ __launch_bounds__(512) void gemm_out(
    const ushort* __restrict__ A, const ushort* __restrict__ B,
    const float* __restrict__ bias, float* __restrict__ C,
    int M, int N, int K)
{
  __shared__ __align__(16) ushort At[2][128 * 32];
  __shared__ __align__(16) ushort Bt[2][128 * 32];
  const int tid = threadIdx.x;
  const int lane = tid & 63, wave = tid >> 6;
  const int wm = wave >> 1, wn = wave & 1;
  const int m0 = blockIdx.y * 128, n0 = blockIdx.x * 128;
  const int row = tid >> 2, kc = tid & 3;
  const size_t aoff = (size_t)(m0 + row) * K + kc * 8;
  const size_t boff = (size_t)(n0 + row) * K + kc * 8;
  const int lchunk = (kc * 128 + row) * 8;

  bf16x8 ra = ld_bf8(A + aoff);
  bf16x8 rb = ld_bf8(B + boff);
  *(bf16x8*)&At[0][lchunk] = ra;
  *(bf16x8*)&Bt[0][lchunk] = rb;
  __syncthreads();

  f32x4 acc[2][4];
  #pragma unroll
  for (int i = 0; i < 2; ++i)
    #pragma unroll
    for (int j = 0; j < 4; ++j) acc[i][j] = (f32x4){0.f, 0.f, 0.f, 0.f};

  for (int t = 0; t < 32; ++t) {
    const int cur = t & 1;
    if (t < 31) {
      ra = ld_bf8(A + aoff + (size_t)(t + 1) * 32);
      rb = ld_bf8(B + boff + (size_t)(t + 1) * 32);
    }
    bf16x8 af[2], bfr[4];
    #pragma unroll
    for (int i = 0; i < 2; ++i)
      af[i] = *(const bf16x8*)&At[cur][((lane >> 4) * 128 + wm * 32 + i * 16 + (lane & 15)) * 8];
    #pragma unroll
    for (int j = 0; j < 4; ++j)
      bfr[j] = *(const bf16x8*)&Bt[cur][((lane >> 4) * 128 + wn * 64 + j * 16 + (lane & 15)) * 8];
    __builtin_amdgcn_s_setprio(1);
    #pragma unroll
    for (int i = 0; i < 2; ++i)
      #pragma unroll
      for (int j = 0; j < 4; ++j)
        acc[i][j] = __builtin_amdgcn_mfma_f32_16x16x32_bf16(af[i], bfr[j], acc[i][j], 0, 0, 0);
    __builtin_amdgcn_s_setprio(0);
    if (t < 31) {
      *(bf16x8*)&At[cur ^ 1][lchunk] = ra;
      *(bf16x8*)&Bt[cur ^ 1][lchunk] = rb;
    }
    __syncthreads();
  }

  #pragma unroll
  for (int i = 0; i < 2; ++i) {
    #pragma unroll
    for (int j = 0; j < 4; ++j) {
      #pragma unroll
      for (int r = 0; r < 4; ++r) {
        int m = m0 + wm * 32 + i * 16 + (lane >> 4) * 4 + r;
        int n = n0 + wn * 64 + j * 16 + (lane & 15);
        C[(size_t)m * N + n] = acc[i][j][r] + bias[n];
      }
    }
  }
}

// ---------------- Fused flash-style attention, 128-row blocks (R12 exact) ----------------
__global__ __launch_bounds__(512, 4) void attn_fused(
    const ushort* __restrict__ Qh, const ushort* __restrict__ Kh,
    const ushort* __restrict__ Vt, float* __restrict__ attn,
    ushort* __restrict__ ctxb)
{
  __shared__ __align__(16) ushort sK[2][64 * 64];   // 2 x 8KB, XOR-swizzled
  __shared__ __align__(16) ushort sV[2][64 * 64];   // 2 x 8KB
  __shared__ __align__(16) ushort sP[8][16 * 64];   // per-wave P tiles, 16KB
  __shared__ float sInv[128];

  const int tid = threadIdx.x, lane = tid & 63, wave = tid >> 6;
  const int l16 = lane & 15, lq = lane >> 4;
  const int swz = l16 & 7;
  // XCD swizzle: 512 blocks = 8 XCDs x 64 -> 4 consecutive bh per XCD.
  const int bid  = blockIdx.x;
  const int sbid = (bid & 7) * 64 + (bid >> 3);
  const int bh = sbid >> 4;
  const int q0 = (sbid & 15) * 128;
  const ushort* Qp = Qh + ((size_t)bh * SEQ + q0) * DK;
  const ushort* Kp = Kh + (size_t)bh * SEQ * DK;
  const ushort* Vp = Vt + (size_t)bh * DK * SEQ;

  bf16x8 bq0 = *(const bf16x8*)(Qp + (wave * 16 + l16) * DK + lq * 8);
  bf16x8 bq1 = *(const bf16x8*)(Qp + (wave * 16 + l16) * DK + 32 + lq * 8);

  const int srow = tid >> 3;                         // 0..63 (key or d)
  const int sc   = tid & 7;                          // dk/key chunk
  const int sdst = (srow * 8 + (sc ^ (srow & 7))) * 8;
  const ushort* kgsrc = Kp + (size_t)tid * 8;        // K tile kt: + kt*4096
  const ushort* vgsrc = Vp + (size_t)srow * SEQ + sc * 8;  // V tile kt: + kt*64

  // ================= Pass A: row sums =================
  float lsum = 0.f;
  {
    bf16x8 rk = *(const bf16x8*)kgsrc;
    *(bf16x8*)&sK[0][sdst] = rk;
    __syncthreads();
    for (int kt = 0; kt < 32; ++kt) {
      const int cur = kt & 1;
      if (kt < 31) rk = *(const bf16x8*)(kgsrc + (size_t)(kt + 1) * 4096);
      __builtin_amdgcn_s_setprio(1);
      #pragma unroll
      for (int ni = 0; ni < 4; ++ni) {
        bf16x8 kf0 = *(const bf16x8*)&sK[cur][((ni * 16 + l16) * 8 + (lq ^ swz)) * 8];
        bf16x8 kf1 = *(const bf16x8*)&sK[cur][((ni * 16 + l16) * 8 + ((4 + lq) ^ swz)) * 8];
        f32x4 acc = (f32x4){0.f, 0.f, 0.f, 0.f};
        acc = __builtin_amdgcn_mfma_f32_16x16x32_bf16(kf0, bq0, acc, 0, 0, 0);
        acc = __builtin_amdgcn_mfma_f32_16x16x32_bf16(kf1, bq1, acc, 0, 0, 0);
        lsum += (__expf(acc[0]) + __expf(acc[1])) + (__expf(acc[2]) + __expf(acc[3]));
      }
      __builtin_amdgcn_s_setprio(0);
      if (kt < 31) *(bf16x8*)&sK[cur ^ 1][sdst] = rk;
      __syncthreads();
    }
  }
  lsum += __shfl_xor(lsum, 16);
  lsum += __shfl_xor(lsum, 32);
  if (lane < 16) sInv[wave * 16 + lane] = 1.0f / lsum;  // own-wave use only

  // ================= Pass B: attn emit + PV =================
  f32x4 cacc[4];
  #pragma unroll
  for (int ni = 0; ni < 4; ++ni) cacc[ni] = (f32x4){0.f, 0.f, 0.f, 0.f};
  ushort* myP = sP[wave];
  {
    bf16x8 rk = *(const bf16x8*)kgsrc;
    bf16x8 rv = *(const bf16x8*)vgsrc;
    __syncthreads();                 // all pass-A reads of sK done
    *(bf16x8*)&sK[0][sdst] = rk;
    *(bf16x8*)&sV[0][sdst] = rv;
    __syncthreads();
    for (int kt = 0; kt < 32; ++kt) {
      const int cur = kt & 1;
      if (kt < 31) {
        rk = *(const bf16x8*)(kgsrc + (size_t)(kt + 1) * 4096);
        rv = *(const bf16x8*)(vgsrc + (size_t)(kt + 1) * 64);
      }
      // QK^T + exp -> wave-private P tile
      __builtin_amdgcn_s_setprio(1);
      #pragma unroll
      for (int ni = 0; ni < 4; ++ni) {
        bf16x8 kf0 = *(const bf16x8*)&sK[cur][((ni * 16 + l16) * 8 + (lq ^ swz)) * 8];
        bf16x8 kf1 = *(const bf16x8*)&sK[cur][((ni * 16 + l16) * 8 + ((4 + lq) ^ swz)) * 8];
        f32x4 acc = (f32x4){0.f, 0.f, 0.f, 0.f};
        acc = __builtin_amdgcn_mfma_f32_16x16x32_bf16(kf0, bq0, acc, 0, 0, 0);
        acc = __builtin_amdgcn_mfma_f32_16x16x32_bf16(kf1, bq1, acc, 0, 0, 0);
        ushort4 pk;
        pk.x = f2bf(__expf(acc[0]));
        pk.y = f2bf(__expf(acc[1]));
        pk.z = f2bf(__expf(acc[2]));
        pk.w = f2bf(__expf(acc[3]));
        const int col = ni * 16 + lq * 4;
        *(ushort4*)&myP[(l16 * 8 + ((col >> 3) ^ swz)) * 8 + (col & 7)] = pk;
      }
      // PV from P tile + V tile
      #pragma unroll
      for (int h = 0; h < 2; ++h) {
        bf16x8 pa = *(const bf16x8*)&myP[(l16 * 8 + ((h * 4 + lq) ^ swz)) * 8];
        #pragma unroll
        for (int ni = 0; ni < 4; ++ni) {
          bf16x8 vf = *(const bf16x8*)&sV[cur][((ni * 16 + l16) * 8 + ((h * 4 + lq) ^ swz)) * 8];
          cacc[ni] = __builtin_amdgcn_mfma_f32_16x16x32_bf16(pa, vf, cacc[ni], 0, 0, 0);
        }
      }
      __builtin_amdgcn_s_setprio(0);
      // stage next tile (writes to the buffer no one reads this iteration)
      if (kt < 31) {
        *(bf16x8*)&sK[cur ^ 1][sdst] = rk;
        *(bf16x8*)&sV[cur ^ 1][sdst] = rv;
      }
      // attn store: full-line nontemporal, wave's 16 rows x 64 keys
      {
        const int r4 = lane >> 4, c16 = lane & 15;
        const int col = c16 * 4;
        #pragma unroll
        for (int rg = 0; rg < 4; ++rg) {
          const int pr = rg * 4 + r4;
          const float iv = sInv[wave * 16 + pr];
          ushort4 pv = *(const ushort4*)&myP[(pr * 8 + ((col >> 3) ^ (pr & 7))) * 8 + (col & 7)];
          f32x4 o;
          o[0] = bf2f(pv.x) * iv;
          o[1] = bf2f(pv.y) * iv;
          o[2] = bf2f(pv.z) * iv;
          o[3] = bf2f(pv.w) * iv;
          float* ap = attn + ((size_t)(bh * SEQ + q0 + wave * 16 + pr)) * SEQ + kt * 64 + col;
          __builtin_nontemporal_store(o, (f32x4*)ap);
        }
      }
      __syncthreads();
    }
  }

  // ctx write: wave covers all keys -> acc complete, no cross-wave reduce
  const int bb = bh >> 4, hh = bh & 15;
  #pragma unroll
  for (int ni = 0; ni < 4; ++ni) {
    #pragma unroll
    for (int r = 0; r < 4; ++r) {
      const int qrow = wave * 16 + lq * 4 + r;
      const float iv = sInv[qrow];
      ctxb[((size_t)(bb * SEQ + q0 + qrow)) * D_MODEL + hh * DK + ni * 16 + l16] =
          f2bf(cacc[ni][r] * iv);
    }
  }
}

extern "C" void kernel_launch(void* const* d_in, const int* in_sizes, int n_in,
                              void* d_out, int out_size, void* d_ws, size_t ws_size,
                              hipStream_t stream)
{
  const float* q  = (const float*)d_in[0];
  const float* k  = (const float*)d_in[1];
  const float* v  = (const float*)d_in[2];
  const float* Wq = (const float*)d_in[3];
  const float* bq = (const float*)d_in[4];
  const float* Wk = (const float*)d_in[5];
  const float* bk = (const float*)d_in[6];
  const float* Wv = (const float*)d_in[7];
  const float* bv = (const float*)d_in[8];
  const float* Wo = (const float*)d_in[9];
  const float* bo = (const float*)d_in[10];

  float* out  = (float*)d_out;
  float* attn = out + (size_t)BATCH * SEQ * D_MODEL;

  const size_t XEL = (size_t)BATCH * SEQ * D_MODEL;  // 4 Mi elems
  const size_t WEL = (size_t)D_MODEL * D_MODEL;      // 1 Mi elems
  ushort* qb   = (ushort*)d_ws;
  ushort* kb   = qb + XEL;
  ushort* vb   = kb + XEL;
  ushort* wqb  = vb + XEL;
  ushort* wkb  = wqb + WEL;
  ushort* wvb  = wkb + WEL;
  ushort* wob  = wvb + WEL;
  ushort* Qhb  = wob + WEL;
  ushort* Khb  = Qhb + XEL;
  ushort* Vtb  = Khb + XEL;
  ushort* ctxb = Vtb + XEL;   // total 64 MiB (R3 footprint, fits ws)

  const int M = BATCH * SEQ;
  convert_all<<<dim3(8192), 256, 0, stream>>>(q, k, v, Wq, Wk, Wv, Wo,
                                              qb, kb, vb, wqb, wkb, wvb, wob);

  gemm_qkv<<<dim3(24, M / 128), 512, 0, stream>>>(qb, kb, vb, wqb, wkb, wvb,
                                                  bq, bk, bv, Qhb, Khb, Vtb);

  attn_fused<<<dim3(BATCH * NHEAD * (SEQ / 128)), 512, 0, stream>>>(Qhb, Khb, Vtb, attn, ctxb);

  gemm_out<<<dim3(D_MODEL / 128, M / 128), 512, 0, stream>>>(ctxb, wob, bo, out, M, D_MODEL, D_MODEL);
}

// Round 18
// 222.180 us; speedup vs baseline: 1.1727x; 1.0034x over previous
//
#include <hip/hip_runtime.h>
#include <hip/hip_bf16.h>

#define D_MODEL 1024
#define NHEAD   16
#define DK      64
#define SEQ     2048
#define BATCH   2

typedef __attribute__((ext_vector_type(8))) short bf16x8;   // 8 bf16 = 4 VGPR
typedef __attribute__((ext_vector_type(4))) float f32x4;

static __device__ __forceinline__ ushort f2bf(float f) {
  union { float f; unsigned u; } x; x.f = f;
  unsigned r = x.u + 0x7FFF + ((x.u >> 16) & 1);   // round-to-nearest-even
  return (ushort)(r >> 16);
}
static __device__ __forceinline__ float bf2f(ushort b) {
  union { unsigned u; float f; } x; x.u = ((unsigned)b) << 16;
  return x.f;
}

static __device__ __forceinline__ bf16x8 ld_bf8(const ushort* p) {
  return *(const bf16x8*)p;
}

// ---------------- one-shot fp32 -> bf16 convert (R17 proven) ----------------
__global__ __launch_bounds__(256) void convert_all(
    const float* __restrict__ q, const float* __restrict__ k, const float* __restrict__ v,
    const float* __restrict__ wq, const float* __restrict__ wk,
    const float* __restrict__ wv, const float* __restrict__ wo,
    ushort* __restrict__ qb, ushort* __restrict__ kb, ushort* __restrict__ vb,
    ushort* __restrict__ wqb, ushort* __restrict__ wkb,
    ushort* __restrict__ wvb, ushort* __restrict__ wob)
{
  int bid = blockIdx.x;
  const float* src; ushort* dst; int seg;
  if      (bid < 2048) { src = q;  dst = qb;  seg = bid; }
  else if (bid < 4096) { src = k;  dst = kb;  seg = bid - 2048; }
  else if (bid < 6144) { src = v;  dst = vb;  seg = bid - 4096; }
  else if (bid < 6656) { src = wq; dst = wqb; seg = bid - 6144; }
  else if (bid < 7168) { src = wk; dst = wkb; seg = bid - 6656; }
  else if (bid < 7680) { src = wv; dst = wvb; seg = bid - 7168; }
  else                 { src = wo; dst = wob; seg = bid - 7680; }
  size_t base = (size_t)seg * 2048 + (size_t)threadIdx.x * 8;
  float4 a = *(const float4*)(src + base);
  float4 b = *(const float4*)(src + base + 4);
  bf16x8 o;
  o[0] = (short)f2bf(a.x); o[1] = (short)f2bf(a.y); o[2] = (short)f2bf(a.z); o[3] = (short)f2bf(a.w);
  o[4] = (short)f2bf(b.x); o[5] = (short)f2bf(b.y); o[6] = (short)f2bf(b.z); o[7] = (short)f2bf(b.w);
  *(bf16x8*)(dst + base) = o;
}

// ---------------- Fused QKV projection GEMM (R17 exact) ----------------
__global__ __launch_bounds__(512) void gemm_qkv(
    const ushort* __restrict__ q, const ushort* __restrict__ k, const ushort* __restrict__ v,
    const ushort* __restrict__ Wq, const ushort* __restrict__ Wk, const ushort* __restrict__ Wv,
    const float* __restrict__ bq, const float* __restrict__ bk, const float* __restrict__ bv,
    ushort* __restrict__ Qhb, ushort* __restrict__ Khb, ushort* __restrict__ Vtb)
{
  constexpr int K = D_MODEL;
  __shared__ __align__(16) ushort At[2][128 * 32];
  __shared__ __align__(16) ushort Bt[2][128 * 32];
  const int r = blockIdx.x >> 3;
  const ushort* A    = (r == 0) ? q  : (r == 1) ? k  : v;
  const ushort* W    = (r == 0) ? Wq : (r == 1) ? Wk : Wv;
  const float* bias  = (r == 0) ? bq : (r == 1) ? bk : bv;
  const float outScale = (r == 0) ? 0.125f : 1.0f;

  const int tid = threadIdx.x;
  const int lane = tid & 63, wave = tid >> 6;
  const int wm = wave >> 1, wn = wave & 1;
  const int m0 = blockIdx.y * 128, n0 = (blockIdx.x & 7) * 128;
  const int row = tid >> 2, kc = tid & 3;
  const size_t aoff = (size_t)(m0 + row) * K + kc * 8;
  const size_t boff = (size_t)(n0 + row) * K + kc * 8;
  const int lchunk = (kc * 128 + row) * 8;

  bf16x8 ra = ld_bf8(A + aoff);
  bf16x8 rb = ld_bf8(W + boff);
  *(bf16x8*)&At[0][lchunk] = ra;
  *(bf16x8*)&Bt[0][lchunk] = rb;
  __syncthreads();

  f32x4 acc[2][4];
  #pragma unroll
  for (int i = 0; i < 2; ++i)
    #pragma unroll
    for (int j = 0; j < 4; ++j) acc[i][j] = (f32x4){0.f, 0.f, 0.f, 0.f};

  for (int t = 0; t < 32; ++t) {
    const int cur = t & 1;
    if (t < 31) {
      ra = ld_bf8(A + aoff + (size_t)(t + 1) * 32);
      rb = ld_bf8(W + boff + (size_t)(t + 1) * 32);
    }
    bf16x8 af[2], bfr[4];
    #pragma unroll
    for (int i = 0; i < 2; ++i)
      af[i] = *(const bf16x8*)&At[cur][((lane >> 4) * 128 + wm * 32 + i * 16 + (lane & 15)) * 8];
    #pragma unroll
    for (int j = 0; j < 4; ++j)
      bfr[j] = *(const bf16x8*)&Bt[cur][((lane >> 4) * 128 + wn * 64 + j * 16 + (lane & 15)) * 8];
    __builtin_amdgcn_s_setprio(1);
    #pragma unroll
    for (int i = 0; i < 2; ++i)
      #pragma unroll
      for (int j = 0; j < 4; ++j)
        acc[i][j] = __builtin_amdgcn_mfma_f32_16x16x32_bf16(af[i], bfr[j], acc[i][j], 0, 0, 0);
    __builtin_amdgcn_s_setprio(0);
    if (t < 31) {
      *(bf16x8*)&At[cur ^ 1][lchunk] = ra;
      *(bf16x8*)&Bt[cur ^ 1][lchunk] = rb;
    }
    __syncthreads();
  }

  #pragma unroll
  for (int i = 0; i < 2; ++i) {
    #pragma unroll
    for (int j = 0; j < 4; ++j) {
      #pragma unroll
      for (int rr = 0; rr < 4; ++rr) {
        int m = m0 + wm * 32 + i * 16 + (lane >> 4) * 4 + rr;
        int n = n0 + wn * 64 + j * 16 + (lane & 15);
        float val = (acc[i][j][rr] + bias[n]) * outScale;
        int b = m >> 11, s = m & (SEQ - 1);
        int h = n >> 6,  d = n & (DK - 1);
        if (r == 0)
          Qhb[((size_t)(b * NHEAD + h) * SEQ + s) * DK + d] = f2bf(val);
        else if (r == 1)
          Khb[((size_t)(b * NHEAD + h) * SEQ + s) * DK + d] = f2bf(val);
        else
          Vtb[((size_t)(b * NHEAD + h) * DK + d) * SEQ + s] = f2bf(val);
      }
    }
  }
}

// ---------------- Output GEMM (R17 exact) ----------------
__global__ __launch_bounds__(512) void gemm_out(
    const ushort* __restrict__ A, const ushort* __restrict__ B,
    const float* __restrict__ bias, float* __restrict__ C,
    int M, int N, int K)
{
  __shared__ __align__(16) ushort At[2][128 * 32];
  __shared__ __align__(16) ushort Bt[2][128 * 32];
  const int tid = threadIdx.x;
  const int lane = tid & 63, wave = tid >> 6;
  const int wm = wave >> 1, wn = wave & 1;
  const int m0 = blockIdx.y * 128, n0 = blockIdx.x * 128;
  const int row = tid >> 2, kc = tid & 3;
  const size_t aoff = (size_t)(m0 + row) * K + kc * 8;
  const size_t boff = (size_t)(n0 + row) * K + kc * 8;
  const int lchunk = (kc * 128 + row) * 8;

  bf16x8 ra = ld_bf8(A + aoff);
  bf16x8 rb = ld_bf8(B + boff);
  *(bf16x8*)&At[0][lchunk] = ra;
  *(bf16x8*)&Bt[0][lchunk] = rb;
  __syncthreads();

  f32x4 acc[2][4];
  #pragma unroll
  for (int i = 0; i < 2; ++i)
    #pragma unroll
    for (int j = 0; j < 4; ++j) acc[i][j] = (f32x4){0.f, 0.f, 0.f, 0.f};

  for (int t = 0; t < 32; ++t) {
    const int cur = t & 1;
    if (t < 31) {
      ra = ld_bf8(A + aoff + (size_t)(t + 1) * 32);
      rb = ld_bf8(B + boff + (size_t)(t + 1) * 32);
    }
    bf16x8 af[2], bfr[4];
    #pragma unroll
    for (int i = 0; i < 2; ++i)
      af[i] = *(const bf16x8*)&At[cur][((lane >> 4) * 128 + wm * 32 + i * 16 + (lane & 15)) * 8];
    #pragma unroll
    for (int j = 0; j < 4; ++j)
      bfr[j] = *(const bf16x8*)&Bt[cur][((lane >> 4) * 128 + wn * 64 + j * 16 + (lane & 15)) * 8];
    __builtin_amdgcn_s_setprio(1);
    #pragma unroll
    for (int i = 0; i < 2; ++i)
      #pragma unroll
      for (int j = 0; j < 4; ++j)
        acc[i][j] = __builtin_amdgcn_mfma_f32_16x16x32_bf16(af[i], bfr[j], acc[i][j], 0, 0, 0);
    __builtin_amdgcn_s_setprio(0);
    if (t < 31) {
      *(bf16x8*)&At[cur ^ 1][lchunk] = ra;
      *(bf16x8*)&Bt[cur ^ 1][lchunk] = rb;
    }
    __syncthreads();
  }

  #pragma unroll
  for (int i = 0; i < 2; ++i) {
    #pragma unroll
    for (int j = 0; j < 4; ++j) {
      #pragma unroll
      for (int r = 0; r < 4; ++r) {
        int m = m0 + wm * 32 + i * 16 + (lane >> 4) * 4 + r;
        int n = n0 + wn * 64 + j * 16 + (lane & 15);
        C[(size_t)m * N + n] = acc[i][j][r] + bias[n];
      }
    }
  }
}

// ---------------- Fused flash attention (R12 base; pass A 2-tiles/barrier) ----------------
// R18: pass A processes 2 K-tiles per iteration using 4 K-buffers aliased onto
// the sKV region (sV half is unused in pass A; pass-B's prologue barrier fences
// the alias). Barrier count in pass A: 32 -> 16, zero LDS growth. Per-lane FP
// accumulation order unchanged -> absmax must stay bit-identical.
__global__ __launch_bounds__(512, 4) void attn_fused(
    const ushort* __restrict__ Qh, const ushort* __restrict__ Kh,
    const ushort* __restrict__ Vt, float* __restrict__ attn,
    ushort* __restrict__ ctxb)
{
  __shared__ __align__(16) ushort sKV[4][64 * 64];  // pass A: K x4 | pass B: K x2 + V x2
  __shared__ __align__(16) ushort sP[8][16 * 64];   // per-wave P tiles, 16KB
  __shared__ float sInv[128];

  const int tid = threadIdx.x, lane = tid & 63, wave = tid >> 6;
  const int l16 = lane & 15, lq = lane >> 4;
  const int swz = l16 & 7;
  // XCD swizzle: 512 blocks = 8 XCDs x 64 -> 4 consecutive bh per XCD.
  const int bid  = blockIdx.x;
  const int sbid = (bid & 7) * 64 + (bid >> 3);
  const int bh = sbid >> 4;
  const int q0 = (sbid & 15) * 128;
  const ushort* Qp = Qh + ((size_t)bh * SEQ + q0) * DK;
  const ushort* Kp = Kh + (size_t)bh * SEQ * DK;
  const ushort* Vp = Vt + (size_t)bh * DK * SEQ;

  // Q B-frags for this wave's 16 rows (persistent)
  bf16x8 bq0 = *(const bf16x8*)(Qp + (wave * 16 + l16) * DK + lq * 8);
  bf16x8 bq1 = *(const bf16x8*)(Qp + (wave * 16 + l16) * DK + 32 + lq * 8);

  // staging: thread t loads one 16B chunk per matrix per tile
  const int srow = tid >> 3;                         // 0..63 (key or d)
  const int sc   = tid & 7;                          // dk/key chunk
  const int sdst = (srow * 8 + (sc ^ (srow & 7))) * 8;
  const ushort* kgsrc = Kp + (size_t)tid * 8;        // K tile kt: + kt*4096
  const ushort* vgsrc = Vp + (size_t)srow * SEQ + sc * 8;  // V tile kt: + kt*64

  // ================= Pass A: row sums, 2 tiles per barrier =================
  float lsum = 0.f;
  {
    bf16x8 rk0 = *(const bf16x8*)kgsrc;
    bf16x8 rk1 = *(const bf16x8*)(kgsrc + 4096);
    *(bf16x8*)&sKV[0][sdst] = rk0;
    *(bf16x8*)&sKV[1][sdst] = rk1;
    __syncthreads();
    for (int it = 0; it < 16; ++it) {
      const int p0 = (it & 1) * 2;                   // this iteration's buffer pair
      if (it < 15) {
        rk0 = *(const bf16x8*)(kgsrc + (size_t)(2 * it + 2) * 4096);
        rk1 = *(const bf16x8*)(kgsrc + (size_t)(2 * it + 3) * 4096);
      }
      __builtin_amdgcn_s_setprio(1);
      #pragma unroll
      for (int half = 0; half < 2; ++half) {
        const ushort* kb = sKV[p0 + half];
        #pragma unroll
        for (int ni = 0; ni < 4; ++ni) {
          bf16x8 kf0 = *(const bf16x8*)&kb[((ni * 16 + l16) * 8 + (lq ^ swz)) * 8];
          bf16x8 kf1 = *(const bf16x8*)&kb[((ni * 16 + l16) * 8 + ((4 + lq) ^ swz)) * 8];
          f32x4 acc = (f32x4){0.f, 0.f, 0.f, 0.f};
          acc = __builtin_amdgcn_mfma_f32_16x16x32_bf16(kf0, bq0, acc, 0, 0, 0);
          acc = __builtin_amdgcn_mfma_f32_16x16x32_bf16(kf1, bq1, acc, 0, 0, 0);
          lsum += (__expf(acc[0]) + __expf(acc[1])) + (__expf(acc[2]) + __expf(acc[3]));
        }
      }
      __builtin_amdgcn_s_setprio(0);
      if (it < 15) {
        *(bf16x8*)&sKV[(p0 ^ 2)][sdst] = rk0;
        *(bf16x8*)&sKV[(p0 ^ 2) + 1][sdst] = rk1;
      }
      __syncthreads();
    }
  }
  lsum += __shfl_xor(lsum, 16);
  lsum += __shfl_xor(lsum, 32);
  if (lane < 16) sInv[wave * 16 + lane] = 1.0f / lsum;  // own-wave use only

  // ================= Pass B: attn emit + PV (R12 exact) =================
  ushort (*sK)[64 * 64] = &sKV[0];   // buffers 0,1
  ushort (*sV)[64 * 64] = &sKV[2];   // buffers 2,3
  f32x4 cacc[4];
  #pragma unroll
  for (int ni = 0; ni < 4; ++ni) cacc[ni] = (f32x4){0.f, 0.f, 0.f, 0.f};
  ushort* myP = sP[wave];
  {
    bf16x8 rk = *(const bf16x8*)kgsrc;
    bf16x8 rv = *(const bf16x8*)vgsrc;
    __syncthreads();                 // all pass-A reads of sKV done (fences alias)
    *(bf16x8*)&sK[0][sdst] = rk;
    *(bf16x8*)&sV[0][sdst] = rv;
    __syncthreads();
    for (int kt = 0; kt < 32; ++kt) {
      const int cur = kt & 1;
      if (kt < 31) {
        rk = *(const bf16x8*)(kgsrc + (size_t)(kt + 1) * 4096);
        rv = *(const bf16x8*)(vgsrc + (size_t)(kt + 1) * 64);
      }
      // QK^T + exp -> wave-private P tile
      __builtin_amdgcn_s_setprio(1);
      #pragma unroll
      for (int ni = 0; ni < 4; ++ni) {
        bf16x8 kf0 = *(const bf16x8*)&sK[cur][((ni * 16 + l16) * 8 + (lq ^ swz)) * 8];
        bf16x8 kf1 = *(const bf16x8*)&sK[cur][((ni * 16 + l16) * 8 + ((4 + lq) ^ swz)) * 8];
        f32x4 acc = (f32x4){0.f, 0.f, 0.f, 0.f};
        acc = __builtin_amdgcn_mfma_f32_16x16x32_bf16(kf0, bq0, acc, 0, 0, 0);
        acc = __builtin_amdgcn_mfma_f32_16x16x32_bf16(kf1, bq1, acc, 0, 0, 0);
        ushort4 pk;
        pk.x = f2bf(__expf(acc[0]));
        pk.y = f2bf(__expf(acc[1]));
        pk.z = f2bf(__expf(acc[2]));
        pk.w = f2bf(__expf(acc[3]));
        const int col = ni * 16 + lq * 4;
        *(ushort4*)&myP[(l16 * 8 + ((col >> 3) ^ swz)) * 8 + (col & 7)] = pk;
      }
      // PV from P tile + V tile
      #pragma unroll
      for (int h = 0; h < 2; ++h) {
        bf16x8 pa = *(const bf16x8*)&myP[(l16 * 8 + ((h * 4 + lq) ^ swz)) * 8];
        #pragma unroll
        for (int ni = 0; ni < 4; ++ni) {
          bf16x8 vf = *(const bf16x8*)&sV[cur][((ni * 16 + l16) * 8 + ((h * 4 + lq) ^ swz)) * 8];
          cacc[ni] = __builtin_amdgcn_mfma_f32_16x16x32_bf16(pa, vf, cacc[ni], 0, 0, 0);
        }
      }
      __builtin_amdgcn_s_setprio(0);
      // stage next tile (writes to the buffer no one reads this iteration)
      if (kt < 31) {
        *(bf16x8*)&sK[cur ^ 1][sdst] = rk;
        *(bf16x8*)&sV[cur ^ 1][sdst] = rv;
      }
      // attn store: full-line nontemporal, wave's 16 rows x 64 keys
      {
        const int r4 = lane >> 4, c16 = lane & 15;
        const int col = c16 * 4;
        #pragma unroll
        for (int rg = 0; rg < 4; ++rg) {
          const int pr = rg * 4 + r4;
          const float iv = sInv[wave * 16 + pr];
          ushort4 pv = *(const ushort4*)&myP[(pr * 8 + ((col >> 3) ^ (pr & 7))) * 8 + (col & 7)];
          f32x4 o;
          o[0] = bf2f(pv.x) * iv;
          o[1] = bf2f(pv.y) * iv;
          o[2] = bf2f(pv.z) * iv;
          o[3] = bf2f(pv.w) * iv;
          float* ap = attn + ((size_t)(bh * SEQ + q0 + wave * 16 + pr)) * SEQ + kt * 64 + col;
          __builtin_nontemporal_store(o, (f32x4*)ap);
        }
      }
      __syncthreads();
    }
  }

  // ctx write: wave covers all keys -> acc complete, no cross-wave reduce
  const int bb = bh >> 4, hh = bh & 15;
  #pragma unroll
  for (int ni = 0; ni < 4; ++ni) {
    #pragma unroll
    for (int r = 0; r < 4; ++r) {
      const int qrow = wave * 16 + lq * 4 + r;
      const float iv = sInv[qrow];
      ctxb[((size_t)(bb * SEQ + q0 + qrow)) * D_MODEL + hh * DK + ni * 16 + l16] =
          f2bf(cacc[ni][r] * iv);
    }
  }
}

extern "C" void kernel_launch(void* const* d_in, const int* in_sizes, int n_in,
                              void* d_out, int out_size, void* d_ws, size_t ws_size,
                              hipStream_t stream)
{
  const float* q  = (const float*)d_in[0];
  const float* k  = (const float*)d_in[1];
  const float* v  = (const float*)d_in[2];
  const float* Wq = (const float*)d_in[3];
  const float* bq = (const float*)d_in[4];
  const float* Wk = (const float*)d_in[5];
  const float* bk = (const float*)d_in[6];
  const float* Wv = (const float*)d_in[7];
  const float* bv = (const float*)d_in[8];
  const float* Wo = (const float*)d_in[9];
  const float* bo = (const float*)d_in[10];

  float* out  = (float*)d_out;
  float* attn = out + (size_t)BATCH * SEQ * D_MODEL;

  const size_t XEL = (size_t)BATCH * SEQ * D_MODEL;  // 4 Mi elems
  const size_t WEL = (size_t)D_MODEL * D_MODEL;      // 1 Mi elems
  ushort* qb   = (ushort*)d_ws;
  ushort* kb   = qb + XEL;
  ushort* vb   = kb + XEL;
  ushort* wqb  = vb + XEL;
  ushort* wkb  = wqb + WEL;
  ushort* wvb  = wkb + WEL;
  ushort* wob  = wvb + WEL;
  ushort* Qhb  = wob + WEL;
  ushort* Khb  = Qhb + XEL;
  ushort* Vtb  = Khb + XEL;
  ushort* ctxb = Vtb + XEL;   // total 64 MiB (fits ws)

  const int M = BATCH * SEQ;
  convert_all<<<dim3(8192), 256, 0, stream>>>(q, k, v, Wq, Wk, Wv, Wo,
                                              qb, kb, vb, wqb, wkb, wvb, wob);

  gemm_qkv<<<dim3(24, M / 128), 512, 0, stream>>>(qb, kb, vb, wqb, wkb, wvb,
                                                  bq, bk, bv, Qhb, Khb, Vtb);

  attn_fused<<<dim3(BATCH * NHEAD * (SEQ / 128)), 512, 0, stream>>>(Qhb, Khb, Vtb, attn, ctxb);

  gemm_out<<<dim3(D_MODEL / 128, M / 128), 512, 0, stream>>>(ctxb, wob, bo, out, M, D_MODEL, D_MODEL);
}